// Round 12
// baseline (155.785 us; speedup 1.0000x reference)
//
#include <hip/hip_runtime.h>

#define L_Q 4096
#define D_MODEL 1024
#define N_B 4
#define N_H 8
#define N_P 4
#define M_ROWS (N_B * L_Q)   // 16384

typedef float f32x4 __attribute__((ext_vector_type(4)));
typedef __bf16 bf16x8 __attribute__((ext_vector_type(8)));
typedef unsigned short u16x8 __attribute__((ext_vector_type(8)));

__device__ __forceinline__ unsigned short f2bf(float f) {
    unsigned int u = __float_as_uint(f);
    u += 0x7FFFu + ((u >> 16) & 1u);      // round-to-nearest-even
    return (unsigned short)(u >> 16);
}
__device__ __forceinline__ float bf2f(unsigned short s) {
    return __uint_as_float(((unsigned int)s) << 16);
}

// async global->LDS, 16B per lane; LDS dest = wave-uniform base + lane*16
__device__ __forceinline__ void gload_lds16(const void* g, void* l) {
    __builtin_amdgcn_global_load_lds((const __attribute__((address_space(1))) void*)g,
                                     (__attribute__((address_space(3))) void*)l,
                                     16, 0, 0);
}

template <int N> __device__ __forceinline__ void wait_vmc() {
    if constexpr (N == 6)      asm volatile("s_waitcnt vmcnt(6)"  ::: "memory");
    else if constexpr (N == 5) asm volatile("s_waitcnt vmcnt(5)"  ::: "memory");
    else                       asm volatile("s_waitcnt vmcnt(0)"  ::: "memory");
}

// ---------------- prep kernels ----------------

__global__ void k_cast_value(const float* __restrict__ in, unsigned short* __restrict__ out, int n8) {
    int i = blockIdx.x * blockDim.x + threadIdx.x;
    const int stride = gridDim.x * blockDim.x;
    for (; i < n8; i += stride) {
        float4 a = ((const float4*)in)[2 * i];
        float4 b = ((const float4*)in)[2 * i + 1];
        u16x8 o;
        o[0] = f2bf(a.x); o[1] = f2bf(a.y); o[2] = f2bf(a.z); o[3] = f2bf(a.w);
        o[4] = f2bf(b.x); o[5] = f2bf(b.y); o[6] = f2bf(b.z); o[7] = f2bf(b.w);
        ((u16x8*)out)[i] = o;
    }
}

// WvT/WoT: (N=1024,K=1024) bf16 transposes.
// WcT2: (96, 2048) rows n = [Wh[n](k=0..1023) | Wl[n](k=0..1023)] hi/lo split of [Woff|Wattn]^T.
__global__ void k_prep_weights(const float* __restrict__ Wv, const float* __restrict__ Wo,
                               const float* __restrict__ Woff, const float* __restrict__ Wattn,
                               unsigned short* __restrict__ WvT, unsigned short* __restrict__ WoT,
                               unsigned short* __restrict__ WcT2) {
    const int n1 = D_MODEL * D_MODEL;
    const int n2 = 2 * n1;
    const int n3 = n2 + 96 * 2048;
    int i = blockIdx.x * blockDim.x + threadIdx.x;
    const int stride = gridDim.x * blockDim.x;
    for (; i < n3; i += stride) {
        if (i < n1) {
            int n = i >> 10, k = i & 1023;
            WvT[i] = f2bf(Wv[k * D_MODEL + n]);
        } else if (i < n2) {
            int j = i - n1;
            int n = j >> 10, k = j & 1023;
            WoT[j] = f2bf(Wo[k * D_MODEL + n]);
        } else {
            int j = i - n2;                 // j = row*2048 + half*1024 + k
            int row = j >> 11;
            int rem = j & 2047;
            int half = rem >> 10;
            int k = rem & 1023;
            float w = (row < 64) ? Woff[k * 64 + row] : Wattn[k * 32 + (row - 64)];
            unsigned short h = f2bf(w);
            WcT2[j] = half ? f2bf(w - bf2f(h)) : h;
        }
    }
}

// ---------------- 256x256 two-barrier 8-phase bf16 MFMA GEMM (m201 transcription) ----------------
// C = A(M,K)*Bt(N,K)^T + bias.  M=16384, N=K=1024. 512 threads = 8 waves (2M x 4N).
// Per phase: {ds-reads for THIS phase's MFMA; 1 stage; [lgkmcnt(8) if 12 reads];
//             [vmcnt(6) at p3/p7]; BAR; MFMA (compiler lgkm-guards); BAR}.
// Reads sit BEFORE the first barrier -> they overlap the previous phase's MFMA window via
// wave skew (LDS pipe drains while slow waves still run MFMAs). Checkpoints: vmcnt(6) at
// p3 confirms set1's 4 half-tiles before p4-p7 read them; at p7 confirms next set0.
// Stage plan: p0:A1s1@kt+64 | p1:A0s0' p2:B0s0' p3:B1s0' p4:A1s0' @kt+128 |
//             p5:A0s1' p6:B0s1' p7:B1s1' @kt+192.  All slot WAR gaps >= 1 barrier (verified).
// LDS swizzle: chunk16 ^= (row&7) via inverse-swizzled global source (involution).

template <bool OUT_BF16>
__global__ __launch_bounds__(512, 2) void k_gemm256(const unsigned short* __restrict__ A,
                                                    const unsigned short* __restrict__ Bt,
                                                    const float* __restrict__ bias,
                                                    void* __restrict__ Cout) {
    __shared__ __align__(16) unsigned short lds[2][2][2][8192];  // [mat][set][half][128*64]
    const int tid = threadIdx.x;
    const int w = tid >> 6, lane = tid & 63;
    const int wm = w >> 2, wn = w & 3;

    // XCD-bijective swizzle: 256 blocks = 64(M) x 4(N)
    const int bid = blockIdx.x;
    const int swz = (bid & 7) * 32 + (bid >> 3);
    const int m0 = (swz >> 2) * 256;
    const int n0 = (swz & 3) * 256;

    const int sr = (w << 3) + (lane >> 3);
    const int sc = (lane & 7) ^ ((lane >> 3) & 7);
    const size_t aoff1 = (size_t)(m0 + sr) * 1024 + (size_t)(sc * 8);
    const size_t boff1 = (size_t)(n0 + sr) * 1024 + (size_t)(sc * 8);

    const int fr = lane & 15, kq = lane >> 4;
    const int cs0 = ((kq) ^ (fr & 7)) * 8;
    const int cs1 = ((4 + kq) ^ (fr & 7)) * 8;
    const int arow = (wm * 64 + fr) * 64;
    const int brow = (wn * 32 + fr) * 64;

    f32x4 acc[2][2][4][2];
    const f32x4 zero = {0.f, 0.f, 0.f, 0.f};
#pragma unroll
    for (int qm = 0; qm < 2; ++qm)
#pragma unroll
        for (int qn = 0; qn < 2; ++qn)
#pragma unroll
            for (int i = 0; i < 4; ++i)
#pragma unroll
                for (int j = 0; j < 2; ++j) acc[qm][qn][i][j] = zero;

    bf16x8 af[4][2], bl[2][2], bh[2][2];

#define GSTA(set, half, kt) do {                                                        \
        const unsigned short* g_ = A + aoff1 + (size_t)(half) * 131072 + (size_t)(kt);  \
        unsigned short* d_ = &lds[0][set][half][0] + w * 512;                           \
        gload_lds16(g_, d_);                                                            \
        gload_lds16(g_ + 65536, d_ + 4096);                                             \
    } while (0)

#define GSTB(set, half, kt) do {                                                        \
        const unsigned short* g_ = Bt + boff1 + (size_t)(half) * 131072 + (size_t)(kt); \
        unsigned short* d_ = &lds[1][set][half][0] + w * 512;                           \
        gload_lds16(g_, d_);                                                            \
        gload_lds16(g_ + 65536, d_ + 4096);                                             \
    } while (0)

#define LDA8(set, half) do {                                                            \
        const unsigned short* sA_ = &lds[0][set][half][0];                              \
        _Pragma("unroll") for (int i = 0; i < 4; ++i) {                                 \
            af[i][0] = *(const bf16x8*)(sA_ + arow + i * 1024 + cs0);                   \
            af[i][1] = *(const bf16x8*)(sA_ + arow + i * 1024 + cs1);                   \
        }                                                                               \
    } while (0)

#define LDB4(dst, set, half) do {                                                       \
        const unsigned short* sB_ = &lds[1][set][half][0];                              \
        _Pragma("unroll") for (int j = 0; j < 2; ++j) {                                 \
            dst[j][0] = *(const bf16x8*)(sB_ + brow + j * 1024 + cs0);                  \
            dst[j][1] = *(const bf16x8*)(sB_ + brow + j * 1024 + cs1);                  \
        }                                                                               \
    } while (0)

#define MM16(qm, qn, B_) do {                                                           \
        __builtin_amdgcn_s_setprio(1);                                                  \
        _Pragma("unroll") for (int i = 0; i < 4; ++i)                                   \
        _Pragma("unroll") for (int j = 0; j < 2; ++j)                                   \
        _Pragma("unroll") for (int kk = 0; kk < 2; ++kk)                                \
            acc[qm][qn][i][j] = __builtin_amdgcn_mfma_f32_16x16x32_bf16(                \
                af[i][kk], B_[j][kk], acc[qm][qn][i][j], 0, 0, 0);                      \
        __builtin_amdgcn_s_setprio(0);                                                  \
    } while (0)

#define LGK8() asm volatile("s_waitcnt lgkmcnt(8)" ::: "memory")
#define BAR() do { __builtin_amdgcn_s_barrier(); asm volatile("" ::: "memory"); } while (0)

    // ---- prologue: stage set0@0 (4 half-tiles) + set1@64 partial (A0s1,B0s1,B1s1) ----
    GSTA(0, 0, 0);        // A0s0
    GSTB(0, 0, 0);        // B0s0
    GSTB(0, 1, 0);        // B1s0
    GSTA(0, 1, 0);        // A1s0
    GSTA(1, 0, 64);       // A0s1
    GSTB(1, 0, 64);       // B0s1
    GSTB(1, 1, 64);       // B1s1
    wait_vmc<6>();        // confirms the 4 set0 half-tiles (leaves 3 set1 stages in flight)
    BAR();

#pragma unroll 1
    for (int it = 0; it < 8; ++it) {
        const int kt  = it * 128;
        const int kA  = kt + 64;             // set1 of this iter (A1s1 stage)
        const int ktn = (kt + 128) & 1023;   // next set0 (wrap keeps junk tail in-bounds)
        const int kt2 = (kt + 192) & 1023;   // next set1
        // p0: reads af<-A(s0,h0), bl<-B(s0,h0) [12]; stage A1s1@kA
        LDA8(0, 0); LDB4(bl, 0, 0);
        GSTA(1, 1, kA);
        LGK8();
        BAR();
        MM16(0, 0, bl);
        BAR();
        // p1: reads bh<-B(s0,h1) [4]; stage A0s0'@ktn
        LDB4(bh, 0, 1);
        GSTA(0, 0, ktn);
        BAR();
        MM16(0, 1, bh);
        BAR();
        // p2: reads af<-A(s0,h1) [8]; stage B0s0'@ktn
        LDA8(0, 1);
        GSTB(0, 0, ktn);
        BAR();
        MM16(1, 1, bh);
        BAR();
        // p3: no reads; stage B1s0'@ktn; CHECKPOINT vmcnt(6) (confirms set1 of this iter)
        GSTB(0, 1, ktn);
        wait_vmc<6>();
        BAR();
        MM16(1, 0, bl);
        BAR();
        // p4: reads af<-A(s1,h0), bl<-B(s1,h0) [12]; stage A1s0'@ktn
        LDA8(1, 0); LDB4(bl, 1, 0);
        GSTA(0, 1, ktn);
        LGK8();
        BAR();
        MM16(0, 0, bl);
        BAR();
        // p5: reads bh<-B(s1,h1) [4]; stage A0s1'@kt2
        LDB4(bh, 1, 1);
        GSTA(1, 0, kt2);
        BAR();
        MM16(0, 1, bh);
        BAR();
        // p6: reads af<-A(s1,h1) [8]; stage B0s1'@kt2
        LDA8(1, 1);
        GSTB(1, 0, kt2);
        BAR();
        MM16(1, 1, bh);
        BAR();
        // p7: no reads; stage B1s1'@kt2; CHECKPOINT vmcnt(6) (confirms next set0)
        GSTB(1, 1, kt2);
        wait_vmc<6>();
        BAR();
        MM16(1, 0, bl);
        BAR();
    }
    wait_vmc<0>();   // drain tail junk stages

#undef GSTA
#undef GSTB
#undef LDA8
#undef LDB4
#undef MM16
#undef LGK8
#undef BAR

#pragma unroll
    for (int qm = 0; qm < 2; ++qm) {
#pragma unroll
        for (int qn = 0; qn < 2; ++qn) {
#pragma unroll
            for (int i = 0; i < 4; ++i) {
#pragma unroll
                for (int j = 0; j < 2; ++j) {
                    const int col = n0 + qn * 128 + wn * 32 + j * 16 + fr;
                    const float bcol = bias[col];
#pragma unroll
                    for (int r = 0; r < 4; ++r) {
                        const int row = m0 + qm * 128 + wm * 64 + i * 16 + kq * 4 + r;
                        const float v = acc[qm][qn][i][j][r] + bcol;
                        if (OUT_BF16)
                            ((unsigned short*)Cout)[(size_t)row * D_MODEL + col] = f2bf(v);
                        else
                            ((float*)Cout)[(size_t)row * D_MODEL + col] = v;
                    }
                }
            }
        }
    }
}

// ---------------- off/attn projection, fused hi/lo split ----------------
// C96(M,96) = qhi*Wh + qhi*Wl + qlo*Wh + bias, computed per K-tile (16 tiles of 64).

__global__ __launch_bounds__(512, 2) void k_offattn2(const float* __restrict__ query,
                                                     const unsigned short* __restrict__ WcT2,
                                                     const float* __restrict__ boff,
                                                     const float* __restrict__ battn,
                                                     float* __restrict__ C96) {
    __shared__ __align__(16) unsigned short ldsA[2][128 * 64];  // rows 0-63 hi, 64-127 lo
    __shared__ __align__(16) unsigned short ldsB[2][192 * 64];  // rows 0-95 Wh, 96-191 Wl
    const int tid = threadIdx.x;
    const int w = tid >> 6, lane = tid & 63;
    const int wm = w >> 1, wn = w & 1;
    const int m0 = blockIdx.x * 64;

    const int ar = tid >> 3;
    const int ac = tid & 7;
    const float* qbase = query + (size_t)(m0 + ar) * 1024 + ac * 8;
    const int aw_hi = ar * 64 + ((ac ^ (ar & 7)) * 8);
    const int aw_lo = (64 + ar) * 64 + ((ac ^ (ar & 7)) * 8);

    const int brl = lane >> 3;
    const int bchk = (lane & 7) ^ (brl & 7);

    const int fr = lane & 15, kq = lane >> 4;
    const int cs0 = ((kq) ^ (fr & 7)) * 8;
    const int cs1 = ((4 + kq) ^ (fr & 7)) * 8;
    const int ahr = (wm * 16 + fr) * 64;
    const int alr = (64 + wm * 16 + fr) * 64;

    f32x4 acc[3];
    const f32x4 zero = {0.f, 0.f, 0.f, 0.f};
#pragma unroll
    for (int j = 0; j < 3; ++j) acc[j] = zero;

#define ALOAD(f0_, f1_, kt_) do {                                                       \
        f0_ = *(const float4*)(qbase + (kt_));                                          \
        f1_ = *(const float4*)(qbase + (kt_) + 4);                                      \
    } while (0)

#define BSTAGE(p_, kt_) do {                                                            \
        _Pragma("unroll") for (int i_ = 0; i_ < 3; ++i_) {                              \
            const int sr_ = i_ * 64 + w * 8 + brl;                                      \
            const unsigned short* g_ = WcT2 + ((sr_ < 96)                               \
                    ? ((size_t)sr_ * 2048 + (size_t)(kt_))                              \
                    : ((size_t)(sr_ - 96) * 2048 + 1024 + (size_t)(kt_)))               \
                    + (size_t)(bchk * 8);                                               \
            gload_lds16(g_, &ldsB[p_][(i_ * 64 + w * 8) * 64]);                         \
        }                                                                               \
    } while (0)

#define AWRITE2(p_, f0_, f1_) do {                                                      \
        u16x8 hi_, lo_;                                                                 \
        const float vv_[8] = {f0_.x, f0_.y, f0_.z, f0_.w, f1_.x, f1_.y, f1_.z, f1_.w};  \
        _Pragma("unroll") for (int e_ = 0; e_ < 8; ++e_) {                              \
            hi_[e_] = f2bf(vv_[e_]);                                                    \
            lo_[e_] = f2bf(vv_[e_] - bf2f(hi_[e_]));                                    \
        }                                                                               \
        *(u16x8*)(&ldsA[p_][aw_hi]) = hi_;                                              \
        *(u16x8*)(&ldsA[p_][aw_lo]) = lo_;                                              \
    } while (0)

#define OMM(p_) do {                                                                    \
        const unsigned short* As_ = &ldsA[p_][0];                                       \
        const unsigned short* Bs_ = &ldsB[p_][0];                                       \
        bf16x8 ah0 = *(const bf16x8*)(As_ + ahr + cs0);                                 \
        bf16x8 ah1 = *(const bf16x8*)(As_ + ahr + cs1);                                 \
        bf16x8 al0 = *(const bf16x8*)(As_ + alr + cs0);                                 \
        bf16x8 al1 = *(const bf16x8*)(As_ + alr + cs1);                                 \
        __builtin_amdgcn_s_setprio(1);                                                  \
        _Pragma("unroll") for (int j = 0; j < 3; ++j) {                                 \
            const int br_ = (wn * 48 + j * 16 + fr) * 64;                               \
            bf16x8 wh0 = *(const bf16x8*)(Bs_ + br_ + cs0);                             \
            bf16x8 wh1 = *(const bf16x8*)(Bs_ + br_ + cs1);                             \
            bf16x8 wl0 = *(const bf16x8*)(Bs_ + 6144 + br_ + cs0);                      \
            bf16x8 wl1 = *(const bf16x8*)(Bs_ + 6144 + br_ + cs1);                      \
            acc[j] = __builtin_amdgcn_mfma_f32_16x16x32_bf16(ah0, wh0, acc[j], 0, 0, 0);\
            acc[j] = __builtin_amdgcn_mfma_f32_16x16x32_bf16(ah1, wh1, acc[j], 0, 0, 0);\
            acc[j] = __builtin_amdgcn_mfma_f32_16x16x32_bf16(ah0, wl0, acc[j], 0, 0, 0);\
            acc[j] = __builtin_amdgcn_mfma_f32_16x16x32_bf16(ah1, wl1, acc[j], 0, 0, 0);\
            acc[j] = __builtin_amdgcn_mfma_f32_16x16x32_bf16(al0, wh0, acc[j], 0, 0, 0);\
            acc[j] = __builtin_amdgcn_mfma_f32_16x16x32_bf16(al1, wh1, acc[j], 0, 0, 0);\
        }                                                                               \
        __builtin_amdgcn_s_setprio(0);                                                  \
    } while (0)

#define OBODY(t_, p_, fc0_, fc1_, fn0_, fn1_) do {                                      \
        if ((t_) < 15) {                                                                \
            ALOAD(fn0_, fn1_, ((t_) + 1) * 64);                                         \
            BSTAGE((p_) ^ 1, ((t_) + 1) * 64);                                          \
            wait_vmc<5>();                                                              \
        } else {                                                                        \
            wait_vmc<0>();                                                              \
        }                                                                               \
        AWRITE2(p_, fc0_, fc1_);                                                        \
        asm volatile("s_waitcnt lgkmcnt(0)" ::: "memory");                              \
        __builtin_amdgcn_s_barrier(); asm volatile("" ::: "memory");                    \
        OMM(p_);                                                                        \
        __builtin_amdgcn_s_barrier(); asm volatile("" ::: "memory");                    \
    } while (0)

    float4 a0A, a1A, a0B, a1B;
    ALOAD(a0A, a1A, 0);
    BSTAGE(0, 0);

#pragma unroll 1
    for (int t2 = 0; t2 < 8; ++t2) {
        const int t = t2 * 2;
        OBODY(t,     0, a0A, a1A, a0B, a1B);
        OBODY(t + 1, 1, a0B, a1B, a0A, a1A);
    }

#undef ALOAD
#undef BSTAGE
#undef AWRITE2
#undef OMM
#undef OBODY

#pragma unroll
    for (int j = 0; j < 3; ++j) {
        const int col = wn * 48 + j * 16 + fr;
        const float bcol = (col < 64) ? boff[col] : battn[col - 64];
#pragma unroll
        for (int r = 0; r < 4; ++r) {
            const int row = m0 + wm * 16 + kq * 4 + r;
            C96[(size_t)row * 96 + col] = acc[j][r] + bcol;
        }
    }
}

// ---------------- sampler: softmax + bilinear gather + weighted sum ----------------

__global__ void k_sampler(const float* __restrict__ C96,
                          const unsigned short* __restrict__ vproj,
                          unsigned short* __restrict__ agg) {
    const int row = blockIdx.x;          // b*L + l
    const int b = row >> 12;
    const int l = row & (L_Q - 1);
    const int t = threadIdx.x;

    __shared__ float cv[96];
    if (t < 96) cv[t] = C96[(size_t)row * 96 + t];
    __syncthreads();

    const int h = t >> 5;
    const int dd = (t & 31) * 4;
    const float ref_y = (float)l / 4095.0f;

    float lg[4];
#pragma unroll
    for (int p = 0; p < 4; ++p) lg[p] = cv[64 + h * 4 + p];
    const float mx = fmaxf(fmaxf(lg[0], lg[1]), fmaxf(lg[2], lg[3]));
    float ex[4];
    float es = 0.f;
#pragma unroll
    for (int p = 0; p < 4; ++p) { ex[p] = expf(lg[p] - mx); es += ex[p]; }
    const float inv = 1.0f / es;

    float acc0 = 0.f, acc1 = 0.f, acc2 = 0.f, acc3 = 0.f;
#pragma unroll
    for (int p = 0; p < 4; ++p) {
        const float ox = cv[h * 8 + p * 2];
        const float oy = cv[h * 8 + p * 2 + 1];
        const float lx = fminf(fmaxf(ox, 0.0f), 1.0f);               // ref_x = 0
        const float ly = fminf(fmaxf(ref_y + oy, 0.0f), 1.0f);
        const float ux = (lx + 1.0f) * 2048.0f - 0.5f;               // ((x+1)*L - 1)/2
        const float wy = 1.0f - ly * 0.5f;                           // uy in [0,0.5] -> wy = 1-uy
        const float x0f = floorf(ux);
        const int i0 = (int)x0f;
        const int i1 = i0 + 1;
        const float w1 = ux - x0f;
        const float w0 = 1.0f - w1;
        const float aw = ex[p] * inv * wy;
        const float f0 = aw * w0 * ((i0 >= 0 && i0 < L_Q) ? 1.0f : 0.0f);
        const float f1 = aw * w1 * ((i1 >= 0 && i1 < L_Q) ? 1.0f : 0.0f);
        const int i0c = i0 < 0 ? 0 : (i0 > L_Q - 1 ? L_Q - 1 : i0);
        const int i1c = i1 < 0 ? 0 : (i1 > L_Q - 1 ? L_Q - 1 : i1);
        const ushort4 v0 = *(const ushort4*)(vproj + (size_t)(b * L_Q + i0c) * D_MODEL + h * 128 + dd);
        const ushort4 v1 = *(const ushort4*)(vproj + (size_t)(b * L_Q + i1c) * D_MODEL + h * 128 + dd);
        acc0 += f0 * bf2f(v0.x) + f1 * bf2f(v1.x);
        acc1 += f0 * bf2f(v0.y) + f1 * bf2f(v1.y);
        acc2 += f0 * bf2f(v0.z) + f1 * bf2f(v1.z);
        acc3 += f0 * bf2f(v0.w) + f1 * bf2f(v1.w);
    }
    ushort4 o;
    o.x = f2bf(acc0); o.y = f2bf(acc1); o.z = f2bf(acc2); o.w = f2bf(acc3);
    *(ushort4*)(agg + (size_t)row * D_MODEL + t * 4) = o;
}

// ---------------- launch ----------------

extern "C" void kernel_launch(void* const* d_in, const int* in_sizes, int n_in,
                              void* d_out, int out_size, void* d_ws, size_t ws_size,
                              hipStream_t stream) {
    const float* query = (const float*)d_in[0];
    // d_in[1] key_in: unused (dead code in reference)
    const float* value = (const float*)d_in[2];
    // d_in[3] Wqk, d_in[4] bqk: unused (dead code)
    const float* Wv    = (const float*)d_in[5];
    const float* bv    = (const float*)d_in[6];
    const float* Woff  = (const float*)d_in[7];
    const float* boff  = (const float*)d_in[8];
    const float* Wattn = (const float*)d_in[9];
    const float* battn = (const float*)d_in[10];
    const float* Wo    = (const float*)d_in[11];
    const float* bo    = (const float*)d_in[12];

    char* ws = (char*)d_ws;
    size_t off = 0;
    auto alloc = [&](size_t bytes) -> char* {
        char* p = ws + off;
        off += (bytes + 255) & ~(size_t)255;
        return p;
    };
    unsigned short* val_bf = (unsigned short*)alloc((size_t)M_ROWS * D_MODEL * 2);  // 32MB
    unsigned short* vproj  = (unsigned short*)alloc((size_t)M_ROWS * D_MODEL * 2);  // 32MB
    unsigned short* agg    = (unsigned short*)alloc((size_t)M_ROWS * D_MODEL * 2);  // 32MB
    float*          C96    = (float*)alloc((size_t)M_ROWS * 96 * 4);                // 6MB
    unsigned short* WvT    = (unsigned short*)alloc((size_t)D_MODEL * D_MODEL * 2); // 2MB
    unsigned short* WoT    = (unsigned short*)alloc((size_t)D_MODEL * D_MODEL * 2); // 2MB
    unsigned short* WcT2   = (unsigned short*)alloc((size_t)96 * 2048 * 2);         // 0.4MB

    const int n8 = M_ROWS * D_MODEL / 8;
    k_cast_value<<<4096, 256, 0, stream>>>(value, val_bf, n8);
    k_prep_weights<<<1024, 256, 0, stream>>>(Wv, Wo, Woff, Wattn, WvT, WoT, WcT2);

    // v = value @ Wv + bv   (bf16 out)
    k_gemm256<true><<<256, 512, 0, stream>>>(val_bf, WvT, bv, vproj);

    // C96 = query @ [Woff|Wattn] + [boff|battn]   (fp32-accurate fused hi/lo)
    k_offattn2<<<M_ROWS / 64, 512, 0, stream>>>(query, WcT2, boff, battn, C96);

    // agg = deformable sample + attn-weighted sum  (bf16 out)
    k_sampler<<<M_ROWS, 256, 0, stream>>>(C96, vproj, agg);

    // out = agg @ Wo + bo   (f32 out)
    k_gemm256<false><<<256, 512, 0, stream>>>(agg, WoT, bo, (float*)d_out);
}

// Round 13
// 141.716 us; speedup vs baseline: 1.0993x; 1.0993x over previous
//
#include <hip/hip_runtime.h>

#define L_Q 4096
#define D_MODEL 1024
#define N_B 4
#define N_H 8
#define N_P 4
#define M_ROWS (N_B * L_Q)   // 16384

typedef float f32x4 __attribute__((ext_vector_type(4)));
typedef __bf16 bf16x8 __attribute__((ext_vector_type(8)));
typedef unsigned short u16x8 __attribute__((ext_vector_type(8)));

__device__ __forceinline__ unsigned short f2bf(float f) {
    unsigned int u = __float_as_uint(f);
    u += 0x7FFFu + ((u >> 16) & 1u);      // round-to-nearest-even
    return (unsigned short)(u >> 16);
}
__device__ __forceinline__ float bf2f(unsigned short s) {
    return __uint_as_float(((unsigned int)s) << 16);
}

// async global->LDS, 16B per lane; LDS dest = wave-uniform base + lane*16
__device__ __forceinline__ void gload_lds16(const void* g, void* l) {
    __builtin_amdgcn_global_load_lds((const __attribute__((address_space(1))) void*)g,
                                     (__attribute__((address_space(3))) void*)l,
                                     16, 0, 0);
}

template <int N> __device__ __forceinline__ void wait_vmc() {
    if constexpr (N == 5)      asm volatile("s_waitcnt vmcnt(5)"  ::: "memory");
    else if constexpr (N == 4) asm volatile("s_waitcnt vmcnt(4)"  ::: "memory");
    else                       asm volatile("s_waitcnt vmcnt(0)"  ::: "memory");
}

// ---------------- merged prep kernel ----------------
// blocks 0-255:   WvT 64x64 LDS-tiled transpose (coalesced read + write)
// blocks 256-511: WoT same
// blocks 512-543: WcT2 (96x2048 = [Wh|Wl]) tiled transpose + hi/lo split
// blocks 544+:    value f32 -> bf16 cast, grid-stride, 32B loads

__global__ void k_prep(const float* __restrict__ Wv, const float* __restrict__ Wo,
                       const float* __restrict__ Woff, const float* __restrict__ Wattn,
                       const float* __restrict__ value,
                       unsigned short* __restrict__ WvT, unsigned short* __restrict__ WoT,
                       unsigned short* __restrict__ WcT2, unsigned short* __restrict__ val_bf) {
    __shared__ float tile[64 * 65];
    const int bidx = blockIdx.x;
    const int t = threadIdx.x;

    if (bidx < 512) {
        const float* W = (bidx < 256) ? Wv : Wo;
        unsigned short* WT = (bidx < 256) ? WvT : WoT;
        const int bi = bidx & 255;
        const int k0 = (bi >> 4) * 64, n0 = (bi & 15) * 64;
#pragma unroll
        for (int j = 0; j < 4; ++j) {
            const int r = j * 16 + (t >> 4);
            float4 v = *(const float4*)(W + (size_t)(k0 + r) * 1024 + n0 + (t & 15) * 4);
            float* d = &tile[r * 65 + (t & 15) * 4];
            d[0] = v.x; d[1] = v.y; d[2] = v.z; d[3] = v.w;
        }
        __syncthreads();
#pragma unroll
        for (int j = 0; j < 4; ++j) {
            const int n = j * 16 + (t >> 4);
            const int kc = (t & 15) * 4;
            ushort4 o;
            o.x = f2bf(tile[(kc + 0) * 65 + n]);
            o.y = f2bf(tile[(kc + 1) * 65 + n]);
            o.z = f2bf(tile[(kc + 2) * 65 + n]);
            o.w = f2bf(tile[(kc + 3) * 65 + n]);
            *(ushort4*)(WT + (size_t)(n0 + n) * 1024 + k0 + kc) = o;
        }
    } else if (bidx < 544) {
        const int bi = bidx - 512;
        const int k0 = (bi >> 1) * 64;
        const int ntile = bi & 1;          // 0: Woff (64 cols), 1: Wattn (32 cols)
        const int n0 = ntile * 64;
        const int nw = ntile ? 32 : 64;
        const int ldw = ntile ? 32 : 64;
        const float* W = ntile ? Wattn : Woff;
#pragma unroll
        for (int j = 0; j < 4; ++j) {
            const int r = j * 16 + (t >> 4);
            const int c4 = t & 15;
            if (c4 * 4 < nw) {
                float4 v = *(const float4*)(W + (size_t)(k0 + r) * ldw + c4 * 4);
                float* d = &tile[r * 65 + c4 * 4];
                d[0] = v.x; d[1] = v.y; d[2] = v.z; d[3] = v.w;
            }
        }
        __syncthreads();
#pragma unroll
        for (int j = 0; j < 4; ++j) {
            const int n = j * 16 + (t >> 4);
            if (n < nw) {
                const int kc = (t & 15) * 4;
                ushort4 hi, lo;
                float f0 = tile[(kc + 0) * 65 + n];
                float f1 = tile[(kc + 1) * 65 + n];
                float f2 = tile[(kc + 2) * 65 + n];
                float f3 = tile[(kc + 3) * 65 + n];
                hi.x = f2bf(f0); lo.x = f2bf(f0 - bf2f(hi.x));
                hi.y = f2bf(f1); lo.y = f2bf(f1 - bf2f(hi.y));
                hi.z = f2bf(f2); lo.z = f2bf(f2 - bf2f(hi.z));
                hi.w = f2bf(f3); lo.w = f2bf(f3 - bf2f(hi.w));
                const size_t base = (size_t)(n0 + n) * 2048 + k0 + kc;
                *(ushort4*)(WcT2 + base) = hi;
                *(ushort4*)(WcT2 + base + 1024) = lo;
            }
        }
    } else {
        const int n8 = M_ROWS * D_MODEL / 8;
        int i = (bidx - 544) * 256 + t;
        const int stride = (gridDim.x - 544) * 256;
        for (; i < n8; i += stride) {
            float4 a = ((const float4*)value)[2 * i];
            float4 b = ((const float4*)value)[2 * i + 1];
            u16x8 o;
            o[0] = f2bf(a.x); o[1] = f2bf(a.y); o[2] = f2bf(a.z); o[3] = f2bf(a.w);
            o[4] = f2bf(b.x); o[5] = f2bf(b.y); o[6] = f2bf(b.z); o[7] = f2bf(b.w);
            ((u16x8*)val_bf)[i] = o;
        }
    }
}

// ---------------- 256x256 interleaved-read bf16 MFMA GEMM (R11 best, frozen) ----------------

template <bool OUT_BF16>
__global__ __launch_bounds__(512, 2) void k_gemm256(const unsigned short* __restrict__ A,
                                                    const unsigned short* __restrict__ Bt,
                                                    const float* __restrict__ bias,
                                                    void* __restrict__ Cout) {
    __shared__ __align__(16) unsigned short lds[2][2][2][8192];  // [mat][set][half][128*64]
    const int tid = threadIdx.x;
    const int w = tid >> 6, lane = tid & 63;
    const int wm = w >> 2, wn = w & 3;

    // XCD-bijective swizzle: 256 blocks = 64(M) x 4(N)
    const int bid = blockIdx.x;
    const int swz = (bid & 7) * 32 + (bid >> 3);
    const int m0 = (swz >> 2) * 256;
    const int n0 = (swz & 3) * 256;

    const int sr = (w << 3) + (lane >> 3);
    const int sc = (lane & 7) ^ ((lane >> 3) & 7);
    const size_t aoff1 = (size_t)(m0 + sr) * 1024 + (size_t)(sc * 8);
    const size_t boff1 = (size_t)(n0 + sr) * 1024 + (size_t)(sc * 8);

    const int fr = lane & 15, kq = lane >> 4;
    const int cs0 = ((kq) ^ (fr & 7)) * 8;
    const int cs1 = ((4 + kq) ^ (fr & 7)) * 8;
    const int arow = (wm * 64 + fr) * 64;
    const int brow = (wn * 32 + fr) * 64;

    f32x4 acc[2][2][4][2];
    const f32x4 zero = {0.f, 0.f, 0.f, 0.f};
#pragma unroll
    for (int qm = 0; qm < 2; ++qm)
#pragma unroll
        for (int qn = 0; qn < 2; ++qn)
#pragma unroll
            for (int i = 0; i < 4; ++i)
#pragma unroll
                for (int j = 0; j < 2; ++j) acc[qm][qn][i][j] = zero;

    bf16x8 af[4][2], bl[2][2], bh[2][2];

#define GSTA(set, half, kt) do {                                                        \
        const unsigned short* g_ = A + aoff1 + (size_t)(half) * 131072 + (size_t)(kt);  \
        unsigned short* d_ = &lds[0][set][half][0] + w * 512;                           \
        gload_lds16(g_, d_);                                                            \
        gload_lds16(g_ + 65536, d_ + 4096);                                             \
    } while (0)

#define GSTB(set, half, kt) do {                                                        \
        const unsigned short* g_ = Bt + boff1 + (size_t)(half) * 131072 + (size_t)(kt); \
        unsigned short* d_ = &lds[1][set][half][0] + w * 512;                           \
        gload_lds16(g_, d_);                                                            \
        gload_lds16(g_ + 65536, d_ + 4096);                                             \
    } while (0)

#define MFMA1(qm, qn, i, j, kk, B_)                                                     \
    acc[qm][qn][i][j] = __builtin_amdgcn_mfma_f32_16x16x32_bf16(                        \
        af[i][kk], B_[j][kk], acc[qm][qn][i][j], 0, 0, 0)

#define LDB4(dst, set, half) do {                                                       \
        const unsigned short* sB_ = &lds[1][set][half][0];                              \
        _Pragma("unroll") for (int j = 0; j < 2; ++j) {                                 \
            dst[j][0] = *(const bf16x8*)(sB_ + brow + j * 1024 + cs0);                  \
            dst[j][1] = *(const bf16x8*)(sB_ + brow + j * 1024 + cs1);                  \
        }                                                                               \
    } while (0)

#define LDA8(set, half) do {                                                            \
        const unsigned short* sA_ = &lds[0][set][half][0];                              \
        _Pragma("unroll") for (int i = 0; i < 4; ++i) {                                 \
            af[i][0] = *(const bf16x8*)(sA_ + arow + i * 1024 + cs0);                   \
            af[i][1] = *(const bf16x8*)(sA_ + arow + i * 1024 + cs1);                   \
        }                                                                               \
    } while (0)

#define MM16(qm, qn, B_) do {                                                           \
        _Pragma("unroll") for (int i = 0; i < 4; ++i) {                                 \
            MFMA1(qm, qn, i, 0, 0, B_); MFMA1(qm, qn, i, 0, 1, B_);                     \
            MFMA1(qm, qn, i, 1, 0, B_); MFMA1(qm, qn, i, 1, 1, B_);                     \
        }                                                                               \
    } while (0)

// 16 MFMA with per-i af refill: af[i] is fully consumed by its 4 MFMAs, then refilled.
#define MM16_LDA(qm, qn, B_, setA, halfA) do {                                          \
        const unsigned short* sA_ = &lds[0][setA][halfA][0];                            \
        _Pragma("unroll") for (int i = 0; i < 4; ++i) {                                 \
            MFMA1(qm, qn, i, 0, 0, B_); MFMA1(qm, qn, i, 0, 1, B_);                     \
            MFMA1(qm, qn, i, 1, 0, B_); MFMA1(qm, qn, i, 1, 1, B_);                     \
            af[i][0] = *(const bf16x8*)(sA_ + arow + i * 1024 + cs0);                   \
            af[i][1] = *(const bf16x8*)(sA_ + arow + i * 1024 + cs1);                   \
        }                                                                               \
    } while (0)

#define SGB_MFMA(n) __builtin_amdgcn_sched_group_barrier(0x0008, n, 0)
#define SGB_DSR(n)  __builtin_amdgcn_sched_group_barrier(0x0100, n, 0)
#define PIN_A() do { SGB_DSR(4); SGB_MFMA(16); } while (0)
#define PIN_B() do { SGB_MFMA(4); SGB_DSR(2); SGB_MFMA(4); SGB_DSR(2);                  \
                     SGB_MFMA(4); SGB_DSR(2); SGB_MFMA(4); SGB_DSR(2); } while (0)
#define PIN_D() do { SGB_DSR(4); PIN_B(); } while (0)

#define BAR() do { __builtin_amdgcn_s_barrier(); asm volatile("" ::: "memory"); } while (0)

    // ---- prologue: set0 @ kt=0; read af<-A(0,h0), bl<-B(0,h0) ----
    GSTA(0, 0, 0);        // A0s0
    GSTB(0, 0, 0);        // B0s0
    GSTB(0, 1, 0);        // B1s0
    GSTA(0, 1, 0);        // A1s0
    wait_vmc<4>();        // A0s0, B0s0 landed
    BAR();
    LDA8(0, 0); LDB4(bl, 0, 0);

#pragma unroll 1
    for (int it = 0; it < 8; ++it) {
        const int kt = it * 128;
        const int ktn = (kt + 128) & 1023;   // wrap junk tail stages in-bounds
        // q0: MM(0,0) af x bl(B0 set0); reads bh <- B(0,h1) [free, early]
        GSTA(1, 0, kt + 64);
        wait_vmc<4>(); BAR();
        __builtin_amdgcn_s_setprio(1);
        LDB4(bh, 0, 1);
        MM16(0, 0, bl);
        PIN_A();
        __builtin_amdgcn_s_setprio(0);
        // q1: MM(0,1) af x bh(B1); af[i] <- A(0,h1) rotated
        GSTB(1, 0, kt + 64);
        wait_vmc<4>(); BAR();
        __builtin_amdgcn_s_setprio(1);
        MM16_LDA(0, 1, bh, 0, 1);
        PIN_B();
        __builtin_amdgcn_s_setprio(0);
        // q2: MM(1,1) af x bh; no reads, no vmcnt
        GSTB(1, 1, kt + 64);
        BAR();
        __builtin_amdgcn_s_setprio(1);
        MM16(1, 1, bh);
        __builtin_amdgcn_s_setprio(0);
        // q3: MM(1,0) af x bl(B0); reads bh <- B(1,h0) [early] + af[i] <- A(1,h0)
        GSTA(1, 1, kt + 64);
        wait_vmc<4>(); BAR();
        __builtin_amdgcn_s_setprio(1);
        LDB4(bh, 1, 0);
        MM16_LDA(1, 0, bl, 1, 0);
        PIN_D();
        __builtin_amdgcn_s_setprio(0);
        // q4: MM(0,0) af x bh(B0 set1); reads bl <- B(1,h1)
        GSTA(0, 0, ktn);
        wait_vmc<4>(); BAR();
        __builtin_amdgcn_s_setprio(1);
        LDB4(bl, 1, 1);
        MM16(0, 0, bh);
        PIN_A();
        __builtin_amdgcn_s_setprio(0);
        // q5: MM(0,1) af x bl(B1); af[i] <- A(1,h1)
        GSTB(0, 0, ktn);
        wait_vmc<4>(); BAR();
        __builtin_amdgcn_s_setprio(1);
        MM16_LDA(0, 1, bl, 1, 1);
        PIN_B();
        __builtin_amdgcn_s_setprio(0);
        // q6: MM(1,1) af x bl; no reads, no vmcnt
        GSTB(0, 1, ktn);
        BAR();
        __builtin_amdgcn_s_setprio(1);
        MM16(1, 1, bl);
        __builtin_amdgcn_s_setprio(0);
        // q7: MM(1,0) af x bh(B0); reads bl <- B(0',h0) [early] + af[i] <- A(0',h0)
        GSTA(0, 1, ktn);
        wait_vmc<4>(); BAR();
        __builtin_amdgcn_s_setprio(1);
        LDB4(bl, 0, 0);
        MM16_LDA(1, 0, bh, 0, 0);
        PIN_D();
        __builtin_amdgcn_s_setprio(0);
    }
    wait_vmc<0>();   // drain tail junk stages

#undef GSTA
#undef GSTB
#undef MFMA1
#undef LDB4
#undef LDA8
#undef MM16
#undef MM16_LDA
#undef SGB_MFMA
#undef SGB_DSR
#undef PIN_A
#undef PIN_B
#undef PIN_D
#undef BAR

#pragma unroll
    for (int qm = 0; qm < 2; ++qm) {
#pragma unroll
        for (int qn = 0; qn < 2; ++qn) {
#pragma unroll
            for (int i = 0; i < 4; ++i) {
#pragma unroll
                for (int j = 0; j < 2; ++j) {
                    const int col = n0 + qn * 128 + wn * 32 + j * 16 + fr;
                    const float bcol = bias[col];
#pragma unroll
                    for (int r = 0; r < 4; ++r) {
                        const int row = m0 + qm * 128 + wm * 64 + i * 16 + kq * 4 + r;
                        const float v = acc[qm][qn][i][j][r] + bcol;
                        if (OUT_BF16)
                            ((unsigned short*)Cout)[(size_t)row * D_MODEL + col] = f2bf(v);
                        else
                            ((float*)Cout)[(size_t)row * D_MODEL + col] = v;
                    }
                }
            }
        }
    }
}

// ---------------- off/attn projection, fused hi/lo split ----------------
// C96(M,96) = qhi*Wh + qhi*Wl + qlo*Wh + bias, computed per K-tile (16 tiles of 64).

__global__ __launch_bounds__(512, 2) void k_offattn2(const float* __restrict__ query,
                                                     const unsigned short* __restrict__ WcT2,
                                                     const float* __restrict__ boff,
                                                     const float* __restrict__ battn,
                                                     float* __restrict__ C96) {
    __shared__ __align__(16) unsigned short ldsA[2][128 * 64];  // rows 0-63 hi, 64-127 lo
    __shared__ __align__(16) unsigned short ldsB[2][192 * 64];  // rows 0-95 Wh, 96-191 Wl
    const int tid = threadIdx.x;
    const int w = tid >> 6, lane = tid & 63;
    const int wm = w >> 1, wn = w & 1;
    const int m0 = blockIdx.x * 64;

    const int ar = tid >> 3;
    const int ac = tid & 7;
    const float* qbase = query + (size_t)(m0 + ar) * 1024 + ac * 8;
    const int aw_hi = ar * 64 + ((ac ^ (ar & 7)) * 8);
    const int aw_lo = (64 + ar) * 64 + ((ac ^ (ar & 7)) * 8);

    const int brl = lane >> 3;
    const int bchk = (lane & 7) ^ (brl & 7);

    const int fr = lane & 15, kq = lane >> 4;
    const int cs0 = ((kq) ^ (fr & 7)) * 8;
    const int cs1 = ((4 + kq) ^ (fr & 7)) * 8;
    const int ahr = (wm * 16 + fr) * 64;
    const int alr = (64 + wm * 16 + fr) * 64;

    f32x4 acc[3];
    const f32x4 zero = {0.f, 0.f, 0.f, 0.f};
#pragma unroll
    for (int j = 0; j < 3; ++j) acc[j] = zero;

#define ALOAD(f0_, f1_, kt_) do {                                                       \
        f0_ = *(const float4*)(qbase + (kt_));                                          \
        f1_ = *(const float4*)(qbase + (kt_) + 4);                                      \
    } while (0)

#define BSTAGE(p_, kt_) do {                                                            \
        _Pragma("unroll") for (int i_ = 0; i_ < 3; ++i_) {                              \
            const int sr_ = i_ * 64 + w * 8 + brl;                                      \
            const unsigned short* g_ = WcT2 + ((sr_ < 96)                               \
                    ? ((size_t)sr_ * 2048 + (size_t)(kt_))                              \
                    : ((size_t)(sr_ - 96) * 2048 + 1024 + (size_t)(kt_)))               \
                    + (size_t)(bchk * 8);                                               \
            gload_lds16(g_, &ldsB[p_][(i_ * 64 + w * 8) * 64]);                         \
        }                                                                               \
    } while (0)

#define AWRITE2(p_, f0_, f1_) do {                                                      \
        u16x8 hi_, lo_;                                                                 \
        const float vv_[8] = {f0_.x, f0_.y, f0_.z, f0_.w, f1_.x, f1_.y, f1_.z, f1_.w};  \
        _Pragma("unroll") for (int e_ = 0; e_ < 8; ++e_) {                              \
            hi_[e_] = f2bf(vv_[e_]);                                                    \
            lo_[e_] = f2bf(vv_[e_] - bf2f(hi_[e_]));                                    \
        }                                                                               \
        *(u16x8*)(&ldsA[p_][aw_hi]) = hi_;                                              \
        *(u16x8*)(&ldsA[p_][aw_lo]) = lo_;                                              \
    } while (0)

#define OMM(p_) do {                                                                    \
        const unsigned short* As_ = &ldsA[p_][0];                                       \
        const unsigned short* Bs_ = &ldsB[p_][0];                                       \
        bf16x8 ah0 = *(const bf16x8*)(As_ + ahr + cs0);                                 \
        bf16x8 ah1 = *(const bf16x8*)(As_ + ahr + cs1);                                 \
        bf16x8 al0 = *(const bf16x8*)(As_ + alr + cs0);                                 \
        bf16x8 al1 = *(const bf16x8*)(As_ + alr + cs1);                                 \
        __builtin_amdgcn_s_setprio(1);                                                  \
        _Pragma("unroll") for (int j = 0; j < 3; ++j) {                                 \
            const int br_ = (wn * 48 + j * 16 + fr) * 64;                               \
            bf16x8 wh0 = *(const bf16x8*)(Bs_ + br_ + cs0);                             \
            bf16x8 wh1 = *(const bf16x8*)(Bs_ + br_ + cs1);                             \
            bf16x8 wl0 = *(const bf16x8*)(Bs_ + 6144 + br_ + cs0);                      \
            bf16x8 wl1 = *(const bf16x8*)(Bs_ + 6144 + br_ + cs1);                      \
            acc[j] = __builtin_amdgcn_mfma_f32_16x16x32_bf16(ah0, wh0, acc[j], 0, 0, 0);\
            acc[j] = __builtin_amdgcn_mfma_f32_16x16x32_bf16(ah1, wh1, acc[j], 0, 0, 0);\
            acc[j] = __builtin_amdgcn_mfma_f32_16x16x32_bf16(ah0, wl0, acc[j], 0, 0, 0);\
            acc[j] = __builtin_amdgcn_mfma_f32_16x16x32_bf16(ah1, wl1, acc[j], 0, 0, 0);\
            acc[j] = __builtin_amdgcn_mfma_f32_16x16x32_bf16(al0, wh0, acc[j], 0, 0, 0);\
            acc[j] = __builtin_amdgcn_mfma_f32_16x16x32_bf16(al1, wh1, acc[j], 0, 0, 0);\
        }                                                                               \
        __builtin_amdgcn_s_setprio(0);                                                  \
    } while (0)

#define OBODY(t_, p_, fc0_, fc1_, fn0_, fn1_) do {                                      \
        if ((t_) < 15) {                                                                \
            ALOAD(fn0_, fn1_, ((t_) + 1) * 64);                                         \
            BSTAGE((p_) ^ 1, ((t_) + 1) * 64);                                          \
            wait_vmc<5>();                                                              \
        } else {                                                                        \
            wait_vmc<0>();                                                              \
        }                                                                               \
        AWRITE2(p_, fc0_, fc1_);                                                        \
        asm volatile("s_waitcnt lgkmcnt(0)" ::: "memory");                              \
        __builtin_amdgcn_s_barrier(); asm volatile("" ::: "memory");                    \
        OMM(p_);                                                                        \
        __builtin_amdgcn_s_barrier(); asm volatile("" ::: "memory");                    \
    } while (0)

    float4 a0A, a1A, a0B, a1B;
    ALOAD(a0A, a1A, 0);
    BSTAGE(0, 0);

#pragma unroll 1
    for (int t2 = 0; t2 < 8; ++t2) {
        const int t = t2 * 2;
        OBODY(t,     0, a0A, a1A, a0B, a1B);
        OBODY(t + 1, 1, a0B, a1B, a0A, a1A);
    }

#undef ALOAD
#undef BSTAGE
#undef AWRITE2
#undef OMM
#undef OBODY

#pragma unroll
    for (int j = 0; j < 3; ++j) {
        const int col = wn * 48 + j * 16 + fr;
        const float bcol = (col < 64) ? boff[col] : battn[col - 64];
#pragma unroll
        for (int r = 0; r < 4; ++r) {
            const int row = m0 + wm * 16 + kq * 4 + r;
            C96[(size_t)row * 96 + col] = acc[j][r] + bcol;
        }
    }
}

// ---------------- sampler: softmax + bilinear gather + weighted sum ----------------

__global__ void k_sampler(const float* __restrict__ C96,
                          const unsigned short* __restrict__ vproj,
                          unsigned short* __restrict__ agg) {
    const int row = blockIdx.x;          // b*L + l
    const int b = row >> 12;
    const int l = row & (L_Q - 1);
    const int t = threadIdx.x;

    __shared__ float cv[96];
    if (t < 96) cv[t] = C96[(size_t)row * 96 + t];
    __syncthreads();

    const int h = t >> 5;
    const int dd = (t & 31) * 4;
    const float ref_y = (float)l / 4095.0f;

    float lg[4];
#pragma unroll
    for (int p = 0; p < 4; ++p) lg[p] = cv[64 + h * 4 + p];
    const float mx = fmaxf(fmaxf(lg[0], lg[1]), fmaxf(lg[2], lg[3]));
    float ex[4];
    float es = 0.f;
#pragma unroll
    for (int p = 0; p < 4; ++p) { ex[p] = expf(lg[p] - mx); es += ex[p]; }
    const float inv = 1.0f / es;

    float acc0 = 0.f, acc1 = 0.f, acc2 = 0.f, acc3 = 0.f;
#pragma unroll
    for (int p = 0; p < 4; ++p) {
        const float ox = cv[h * 8 + p * 2];
        const float oy = cv[h * 8 + p * 2 + 1];
        const float lx = fminf(fmaxf(ox, 0.0f), 1.0f);               // ref_x = 0
        const float ly = fminf(fmaxf(ref_y + oy, 0.0f), 1.0f);
        const float ux = (lx + 1.0f) * 2048.0f - 0.5f;               // ((x+1)*L - 1)/2
        const float wy = 1.0f - ly * 0.5f;                           // uy in [0,0.5] -> wy = 1-uy
        const float x0f = floorf(ux);
        const int i0 = (int)x0f;
        const int i1 = i0 + 1;
        const float w1 = ux - x0f;
        const float w0 = 1.0f - w1;
        const float aw = ex[p] * inv * wy;
        const float f0 = aw * w0 * ((i0 >= 0 && i0 < L_Q) ? 1.0f : 0.0f);
        const float f1 = aw * w1 * ((i1 >= 0 && i1 < L_Q) ? 1.0f : 0.0f);
        const int i0c = i0 < 0 ? 0 : (i0 > L_Q - 1 ? L_Q - 1 : i0);
        const int i1c = i1 < 0 ? 0 : (i1 > L_Q - 1 ? L_Q - 1 : i1);
        const ushort4 v0 = *(const ushort4*)(vproj + (size_t)(b * L_Q + i0c) * D_MODEL + h * 128 + dd);
        const ushort4 v1 = *(const ushort4*)(vproj + (size_t)(b * L_Q + i1c) * D_MODEL + h * 128 + dd);
        acc0 += f0 * bf2f(v0.x) + f1 * bf2f(v1.x);
        acc1 += f0 * bf2f(v0.y) + f1 * bf2f(v1.y);
        acc2 += f0 * bf2f(v0.z) + f1 * bf2f(v1.z);
        acc3 += f0 * bf2f(v0.w) + f1 * bf2f(v1.w);
    }
    ushort4 o;
    o.x = f2bf(acc0); o.y = f2bf(acc1); o.z = f2bf(acc2); o.w = f2bf(acc3);
    *(ushort4*)(agg + (size_t)row * D_MODEL + t * 4) = o;
}

// ---------------- launch ----------------

extern "C" void kernel_launch(void* const* d_in, const int* in_sizes, int n_in,
                              void* d_out, int out_size, void* d_ws, size_t ws_size,
                              hipStream_t stream) {
    const float* query = (const float*)d_in[0];
    // d_in[1] key_in: unused (dead code in reference)
    const float* value = (const float*)d_in[2];
    // d_in[3] Wqk, d_in[4] bqk: unused (dead code)
    const float* Wv    = (const float*)d_in[5];
    const float* bv    = (const float*)d_in[6];
    const float* Woff  = (const float*)d_in[7];
    const float* boff  = (const float*)d_in[8];
    const float* Wattn = (const float*)d_in[9];
    const float* battn = (const float*)d_in[10];
    const float* Wo    = (const float*)d_in[11];
    const float* bo    = (const float*)d_in[12];

    char* ws = (char*)d_ws;
    size_t off = 0;
    auto alloc = [&](size_t bytes) -> char* {
        char* p = ws + off;
        off += (bytes + 255) & ~(size_t)255;
        return p;
    };
    unsigned short* val_bf = (unsigned short*)alloc((size_t)M_ROWS * D_MODEL * 2);  // 32MB
    unsigned short* vproj  = (unsigned short*)alloc((size_t)M_ROWS * D_MODEL * 2);  // 32MB
    unsigned short* agg    = (unsigned short*)alloc((size_t)M_ROWS * D_MODEL * 2);  // 32MB
    float*          C96    = (float*)alloc((size_t)M_ROWS * 96 * 4);                // 6MB
    unsigned short* WvT    = (unsigned short*)alloc((size_t)D_MODEL * D_MODEL * 2); // 2MB
    unsigned short* WoT    = (unsigned short*)alloc((size_t)D_MODEL * D_MODEL * 2); // 2MB
    unsigned short* WcT2   = (unsigned short*)alloc((size_t)96 * 2048 * 2);         // 0.4MB

    // prep: tiled transposes (blocks 0-543) + value cast (blocks 544+)
    k_prep<<<2048, 256, 0, stream>>>(Wv, Wo, Woff, Wattn, value, WvT, WoT, WcT2, val_bf);

    // v = value @ Wv + bv   (bf16 out)
    k_gemm256<true><<<256, 512, 0, stream>>>(val_bf, WvT, bv, vproj);

    // C96 = query @ [Woff|Wattn] + [boff|battn]   (fp32-accurate fused hi/lo)
    k_offattn2<<<M_ROWS / 64, 512, 0, stream>>>(query, WcT2, boff, battn, C96);

    // agg = deformable sample + attn-weighted sum  (bf16 out)
    k_sampler<<<M_ROWS, 256, 0, stream>>>(C96, vproj, agg);

    // out = agg @ Wo + bo   (f32 out)
    k_gemm256<false><<<256, 512, 0, stream>>>(agg, WoT, bo, (float*)d_out);
}